// Round 6
// baseline (373.363 us; speedup 1.0000x reference)
//
#include <hip/hip_runtime.h>
#include <cstdint>

#define DIN 256
#define DH 128
#define DOUT 32

typedef short s16x8 __attribute__((ext_vector_type(8)));
typedef float f32x4 __attribute__((ext_vector_type(4)));

__device__ inline ushort f2bf(float f) {
    uint u = __float_as_uint(f);
    u += 0x7fff + ((u >> 16) & 1);   // round-to-nearest-even
    return (ushort)(u >> 16);
}
__device__ inline float bf_lo(uint u) { return __uint_as_float(u << 16); }
__device__ inline float bf_hi(uint u) { return __uint_as_float(u & 0xffff0000u); }
__device__ inline float bfs(ushort u) { return __uint_as_float((uint)u << 16); }

// ---------------- degree / normalization ----------------

__global__ void k_init_deg(int* deg, int n) {
    int i = blockIdx.x * blockDim.x + threadIdx.x;
    if (i < n) deg[i] = 1;  // self-loop contributes 1
}

__global__ void k_count(const int* __restrict__ dst, int* __restrict__ deg, int e) {
    int i = blockIdx.x * blockDim.x + threadIdx.x;
    if (i < e) atomicAdd(&deg[dst[i]], 1);
}

__global__ void k_dis(const int* __restrict__ deg, float* __restrict__ dis, int n) {
    int i = blockIdx.x * blockDim.x + threadIdx.x;
    if (i < n) dis[i] = rsqrtf((float)deg[i]);
}

// ---------------- CSR build ----------------

__global__ __launch_bounds__(256) void k_scan1(const int* __restrict__ deg,
                                               int* __restrict__ offs,
                                               int* __restrict__ bsum, int n) {
    __shared__ int sh[256];
    int base = blockIdx.x * 1024;
    int t = threadIdx.x;
    int v[4];
    int sum = 0;
    #pragma unroll
    for (int j = 0; j < 4; ++j) {
        int i = base + t * 4 + j;
        int d = (i < n) ? (deg[i] - 1) : 0;
        v[j] = sum;
        sum += d;
    }
    sh[t] = sum;
    __syncthreads();
    #pragma unroll
    for (int off = 1; off < 256; off <<= 1) {
        int x = (t >= off) ? sh[t - off] : 0;
        __syncthreads();
        if (t >= off) sh[t] += x;
        __syncthreads();
    }
    int excl = (t == 0) ? 0 : sh[t - 1];
    if (t == 255) bsum[blockIdx.x] = sh[255];
    #pragma unroll
    for (int j = 0; j < 4; ++j) {
        int i = base + t * 4 + j;
        if (i < n) offs[i] = excl + v[j];
    }
}

__global__ __launch_bounds__(256) void k_scan2(int* __restrict__ bsum, int nb) {
    __shared__ int sh[256];
    int t = threadIdx.x;
    sh[t] = (t < nb) ? bsum[t] : 0;
    __syncthreads();
    #pragma unroll
    for (int off = 1; off < 256; off <<= 1) {
        int x = (t >= off) ? sh[t - off] : 0;
        __syncthreads();
        if (t >= off) sh[t] += x;
        __syncthreads();
    }
    int excl = (t == 0) ? 0 : sh[t - 1];
    if (t < nb) bsum[t] = excl;
}

__global__ void k_scan3(int* __restrict__ offs, int* __restrict__ cursor,
                        const int* __restrict__ bsum, int n) {
    int i = blockIdx.x * blockDim.x + threadIdx.x;
    if (i < n) {
        int o = offs[i] + bsum[i >> 10];
        offs[i] = o;
        cursor[i] = o;
    }
}

// ---------------- fill: XCD-ownership partitioned by dst range ----------------
// blocks round-robin across 8 XCDs => blockIdx&7 groups co-resident blocks.
// Range r owns dst in [r*n/8, (r+1)*n/8): its adj/cursor window (~850KB) stays
// in ONE XCD's L2 and accumulates all its 4B writes before writeback.

__global__ __launch_bounds__(256) void k_fill(
    const int* __restrict__ src, const int* __restrict__ dst,
    int* __restrict__ cursor, int* __restrict__ adj, int e, int n) {
    int r = blockIdx.x & 7;
    int q = blockIdx.x >> 3;
    int nq = gridDim.x >> 3;
    int lo = (int)((long long)n * r >> 3);
    int hi = (int)((long long)n * (r + 1) >> 3);
    for (int i = q * blockDim.x + threadIdx.x; i < e; i += nq * blockDim.x) {
        int d = dst[i];
        if (d < lo || d >= hi) continue;
        int s = src[i];
        int pos = atomicAdd(&cursor[d], 1);
        adj[pos] = s;
    }
}

// ---------------- GEMM1 (bf16 MFMA): hs = bf16( (x @ W1) * dis[row] ) ----------------

__global__ __launch_bounds__(256) void k_gemm1(
    const float* __restrict__ x, const float* __restrict__ W1,
    const float* __restrict__ dis, ushort* __restrict__ hs, int n) {
    __shared__ union {
        ushort w1t[128][136];   // [col][k_local]
        ushort cs[128][136];    // epilogue staging
    } u;
    __shared__ ushort xs[128][72];

    int tid = threadIdx.x;
    int row0 = blockIdx.x * 128;
    int lane = tid & 63;
    int w = tid >> 6;
    int wr0 = w * 32;
    int l15 = lane & 15;
    int koff = (lane >> 4) * 8;

    f32x4 acc[2][8];
    #pragma unroll
    for (int i = 0; i < 2; ++i)
        #pragma unroll
        for (int j = 0; j < 8; ++j)
            acc[i][j] = (f32x4){0.f, 0.f, 0.f, 0.f};

    for (int kh = 0; kh < 2; ++kh) {
        {   // stage W1^T half: w1t[c][kl] = W1[kh*128+kl][c]
            int kl = tid >> 1;
            int ch = (tid & 1) * 64;
            const float4* wr = (const float4*)(W1 + (size_t)(kh * 128 + kl) * DH + ch);
            #pragma unroll
            for (int c4 = 0; c4 < 16; ++c4) {
                float4 v = wr[c4];
                u.w1t[ch + c4 * 4 + 0][kl] = f2bf(v.x);
                u.w1t[ch + c4 * 4 + 1][kl] = f2bf(v.y);
                u.w1t[ch + c4 * 4 + 2][kl] = f2bf(v.z);
                u.w1t[ch + c4 * 4 + 3][kl] = f2bf(v.w);
            }
        }
        for (int kc2 = 0; kc2 < 2; ++kc2) {
            {   // stage x tile: 128 rows x 64 k (fp32 -> bf16)
                int r = tid >> 1;
                int half = (tid & 1) * 32;
                int rr = row0 + r; if (rr >= n) rr = n - 1;
                const float4* xr = (const float4*)(x + (size_t)rr * DIN + kh * 128 + kc2 * 64 + half);
                float4 v[8];
                #pragma unroll
                for (int q = 0; q < 8; ++q) v[q] = xr[q];
                #pragma unroll
                for (int q = 0; q < 8; ++q) {
                    ushort4 o;
                    o.x = f2bf(v[q].x); o.y = f2bf(v[q].y);
                    o.z = f2bf(v[q].z); o.w = f2bf(v[q].w);
                    *(ushort4*)&xs[r][half + q * 4] = o;
                }
            }
            __syncthreads();
            #pragma unroll
            for (int kk = 0; kk < 64; kk += 32) {
                s16x8 a0 = *(const s16x8*)&xs[wr0 + l15][kk + koff];
                s16x8 a1 = *(const s16x8*)&xs[wr0 + 16 + l15][kk + koff];
                int kl = kc2 * 64 + kk + koff;
                #pragma unroll
                for (int ct = 0; ct < 8; ++ct) {
                    s16x8 b = *(const s16x8*)&u.w1t[ct * 16 + l15][kl];
                    acc[0][ct] = __builtin_amdgcn_mfma_f32_16x16x32_bf16(a0, b, acc[0][ct], 0, 0, 0);
                    acc[1][ct] = __builtin_amdgcn_mfma_f32_16x16x32_bf16(a1, b, acc[1][ct], 0, 0, 0);
                }
            }
            __syncthreads();
        }
    }

    // epilogue: scale by dis[row], pack bf16, stage through LDS, coalesced store
    float dv[2][4];
    #pragma unroll
    for (int rt = 0; rt < 2; ++rt)
        #pragma unroll
        for (int r = 0; r < 4; ++r) {
            int rg = row0 + wr0 + rt * 16 + (lane >> 4) * 4 + r;
            if (rg >= n) rg = n - 1;
            dv[rt][r] = dis[rg];
        }
    #pragma unroll
    for (int rt = 0; rt < 2; ++rt)
        #pragma unroll
        for (int ct = 0; ct < 8; ++ct)
            #pragma unroll
            for (int r = 0; r < 4; ++r)
                u.cs[wr0 + rt * 16 + (lane >> 4) * 4 + r][ct * 16 + l15] = f2bf(acc[rt][ct][r] * dv[rt][r]);
    __syncthreads();
    {
        int r = tid >> 1;
        int half = (tid & 1) * 64;
        if (row0 + r < n) {
            uint4* dstp = (uint4*)(hs + (size_t)(row0 + r) * DH + half);
            const uint4* s = (const uint4*)&u.cs[r][half];
            #pragma unroll
            for (int q = 0; q < 8; ++q) dstp[q] = s[q];
        }
    }
}

// ---------------- agg1 (fused): h1 = bf16(relu( dis[d]*(hs[d]+sum_nb hs[s]) + b1 )) ----

__global__ __launch_bounds__(256) void k_agg1(
    const ushort* __restrict__ hs, const float* __restrict__ dis,
    const int* __restrict__ offs, const int* __restrict__ deg,
    const int* __restrict__ adj, const float* __restrict__ b1,
    ushort* __restrict__ h1, int n) {
    int node = blockIdx.x * 4 + (threadIdx.x >> 6);
    if (node >= n) return;
    int lane = threadIdx.x & 63;
    const uint* hu = (const uint*)hs;          // row stride 64 uints
    uint us = hu[(size_t)node * 64 + lane];
    float2 acc;
    acc.x = bf_lo(us);
    acc.y = bf_hi(us);

    int off = offs[node];
    int cnt = deg[node] - 1;
    int k = 0;
    for (; k + 3 < cnt; k += 4) {
        int s0 = adj[off + k], s1 = adj[off + k + 1];
        int s2 = adj[off + k + 2], s3 = adj[off + k + 3];
        uint v0 = hu[(size_t)s0 * 64 + lane];
        uint v1 = hu[(size_t)s1 * 64 + lane];
        uint v2 = hu[(size_t)s2 * 64 + lane];
        uint v3 = hu[(size_t)s3 * 64 + lane];
        acc.x += bf_lo(v0) + bf_lo(v1) + bf_lo(v2) + bf_lo(v3);
        acc.y += bf_hi(v0) + bf_hi(v1) + bf_hi(v2) + bf_hi(v3);
    }
    for (; k < cnt; ++k) {
        uint v0 = hu[(size_t)adj[off + k] * 64 + lane];
        acc.x += bf_lo(v0);
        acc.y += bf_hi(v0);
    }
    float dv = dis[node];
    float2 b = *(const float2*)(b1 + lane * 2);
    float rx = fmaxf(acc.x * dv + b.x, 0.f);
    float ry = fmaxf(acc.y * dv + b.y, 0.f);
    uint po = (uint)f2bf(rx) | ((uint)f2bf(ry) << 16);
    ((uint*)h1)[(size_t)node * 64 + lane] = po;
}

// ---------------- GEMM2: h2s = bf16( (h1 @ W2) * dis[row] ) ----------------

__global__ __launch_bounds__(256) void k_gemm2(
    const ushort* __restrict__ h1, const float* __restrict__ W2,
    const float* __restrict__ dis, ushort* __restrict__ h2s, int n) {
    int t = blockIdx.x * blockDim.x + threadIdx.x;
    int row = t >> 3;
    int cg = t & 7;
    if (row >= n) return;
    const uint2* hr = (const uint2*)(h1 + (size_t)row * DH);
    const float4* w4 = (const float4*)W2;
    float4 acc = make_float4(0.f, 0.f, 0.f, 0.f);
    #pragma unroll 8
    for (int k4 = 0; k4 < DH / 4; ++k4) {
        uint2 au = hr[k4];
        float a0 = bf_lo(au.x), a1 = bf_hi(au.x), a2 = bf_lo(au.y), a3 = bf_hi(au.y);
        float4 w0 = w4[(k4 * 4 + 0) * 8 + cg];
        float4 w1 = w4[(k4 * 4 + 1) * 8 + cg];
        float4 w2 = w4[(k4 * 4 + 2) * 8 + cg];
        float4 w3 = w4[(k4 * 4 + 3) * 8 + cg];
        acc.x += a0 * w0.x + a1 * w1.x + a2 * w2.x + a3 * w3.x;
        acc.y += a0 * w0.y + a1 * w1.y + a2 * w2.y + a3 * w3.y;
        acc.z += a0 * w0.z + a1 * w1.z + a2 * w2.z + a3 * w3.z;
        acc.w += a0 * w0.w + a1 * w1.w + a2 * w2.w + a3 * w3.w;
    }
    float dv = dis[row];
    ushort4 o;
    o.x = f2bf(acc.x * dv); o.y = f2bf(acc.y * dv);
    o.z = f2bf(acc.z * dv); o.w = f2bf(acc.w * dv);
    *(ushort4*)(h2s + (size_t)row * DOUT + cg * 4) = o;
}

// ---------------- agg2 + bias + log_softmax fused ----------------

__global__ __launch_bounds__(256) void k_agg2_lsm(
    const ushort* __restrict__ h2s, const float* __restrict__ dis,
    const int* __restrict__ offs, const int* __restrict__ deg,
    const int* __restrict__ adj, const float* __restrict__ b2,
    float* __restrict__ out, int n) {
    int node = blockIdx.x * 8 + (threadIdx.x >> 5);
    if (node >= n) return;
    int c = threadIdx.x & 31;
    float acc = bfs(h2s[(size_t)node * DOUT + c]);

    int off = offs[node];
    int cnt = deg[node] - 1;
    int k = 0;
    for (; k + 3 < cnt; k += 4) {
        int s0 = adj[off + k], s1 = adj[off + k + 1];
        int s2 = adj[off + k + 2], s3 = adj[off + k + 3];
        acc += bfs(h2s[(size_t)s0 * DOUT + c]) + bfs(h2s[(size_t)s1 * DOUT + c])
             + bfs(h2s[(size_t)s2 * DOUT + c]) + bfs(h2s[(size_t)s3 * DOUT + c]);
    }
    for (; k < cnt; ++k) {
        acc += bfs(h2s[(size_t)adj[off + k] * DOUT + c]);
    }
    float v = acc * dis[node] + b2[c];
    float m = v;
    #pragma unroll
    for (int o = 16; o > 0; o >>= 1) m = fmaxf(m, __shfl_xor(m, o));
    float ev = __expf(v - m);
    float s = ev;
    #pragma unroll
    for (int o = 16; o > 0; o >>= 1) s += __shfl_xor(s, o);
    out[(size_t)node * DOUT + c] = v - m - __logf(s);
}

extern "C" void kernel_launch(void* const* d_in, const int* in_sizes, int n_in,
                              void* d_out, int out_size, void* d_ws, size_t ws_size,
                              hipStream_t stream) {
    const float* x  = (const float*)d_in[0];
    const int*   ei = (const int*)d_in[1];
    const float* W1 = (const float*)d_in[2];
    const float* b1 = (const float*)d_in[3];
    const float* W2 = (const float*)d_in[4];
    const float* b2 = (const float*)d_in[5];
    int n = in_sizes[0] / DIN;
    int e = in_sizes[1] / 2;
    const int* src = ei;
    const int* dst = ei + e;
    float* out = (float*)d_out;

    // workspace: deg|offs|cursor|bsum|dis|adj|hs(bf16)|h1(bf16)|h2s(bf16)  ~66 MB
    char* p = (char*)d_ws;
    int*    deg    = (int*)p;     p += (size_t)n * 4;
    int*    offs   = (int*)p;     p += (size_t)n * 4;
    int*    cursor = (int*)p;     p += (size_t)n * 4;
    int*    bsum   = (int*)p;     p += 1024;
    float*  dis    = (float*)p;   p += (size_t)n * 4;
    int*    adj    = (int*)p;     p += (size_t)e * 4;
    ushort* hs     = (ushort*)p;  p += (size_t)n * DH * 2;
    ushort* h1     = (ushort*)p;  p += (size_t)n * DH * 2;
    ushort* h2s    = (ushort*)p;

    int nb = (n + 1023) / 1024;

    k_init_deg<<<(n + 255) / 256, 256, 0, stream>>>(deg, n);
    k_count<<<(e + 255) / 256, 256, 0, stream>>>(dst, deg, e);
    k_dis<<<(n + 255) / 256, 256, 0, stream>>>(deg, dis, n);
    k_scan1<<<nb, 256, 0, stream>>>(deg, offs, bsum, n);
    k_scan2<<<1, 256, 0, stream>>>(bsum, nb);
    k_scan3<<<(n + 255) / 256, 256, 0, stream>>>(offs, cursor, bsum, n);
    k_fill<<<1024, 256, 0, stream>>>(src, dst, cursor, adj, e, n);

    k_gemm1<<<(n + 127) / 128, 256, 0, stream>>>(x, W1, dis, hs, n);
    k_agg1<<<(n + 3) / 4, 256, 0, stream>>>(hs, dis, offs, deg, adj, b1, h1, n);
    k_gemm2<<<(n * 8 + 255) / 256, 256, 0, stream>>>(h1, W2, dis, h2s, n);
    k_agg2_lsm<<<(n + 7) / 8, 256, 0, stream>>>(h2s, dis, offs, deg, adj, b2, out, n);
}